// Round 1
// baseline (161.881 us; speedup 1.0000x reference)
//
#include <hip/hip_runtime.h>

#define HW    16384   // H*W
#define WDIM  128
#define CDIM  64
#define BDIM  32

// ws layout (doubles): [0]=sum f, [1]=sum f^2, [2]=dis partial, [3]=A1, [4]=A2

// One block per (b,c). Single pass: argmax + weighted sums, then closed-form dis.
__global__ __launch_bounds__(256) void k1_channel(const float* __restrict__ feat,
                                                  double* __restrict__ ws) {
    const int t = threadIdx.x;
    const size_t base = (size_t)blockIdx.x * HW;
    const float4* f4 = (const float4*)(feat + base);

    float best = -INFINITY; int bidx = 0;
    float sf = 0.f, s0 = 0.f, si = 0.f, sj = 0.f, sq = 0.f;

    #pragma unroll
    for (int k = 0; k < 16; ++k) {
        int p = t + k * 256;          // float4 index in [0,4096)
        float4 v = f4[p];
        int e = p * 4;                // element index in [0,16384)
        int i  = e >> 7;              // row
        int jb = e & 127;             // col of lane 0 (multiple of 4 -> no row crossing)
        float x0 = v.x, x1 = v.y, x2 = v.z, x3 = v.w;
        // first-occurrence argmax (strict >, increasing flat index)
        if (x0 > best) { best = x0; bidx = e;     }
        if (x1 > best) { best = x1; bidx = e + 1; }
        if (x2 > best) { best = x2; bidx = e + 2; }
        if (x3 > best) { best = x3; bidx = e + 3; }
        float q0 = x0*x0, q1 = x1*x1, q2 = x2*x2, q3 = x3*x3;
        float qs = q0 + q1 + q2 + q3;
        sf += x0 + x1 + x2 + x3;
        s0 += qs;
        si += qs * (float)i;
        sj += q0*(float)jb + q1*(float)(jb+1) + q2*(float)(jb+2) + q3*(float)(jb+3);
        float ii = (float)(i * i);
        sq += q0*(ii + (float)( jb   * jb   ))
            + q1*(ii + (float)((jb+1)*(jb+1)))
            + q2*(ii + (float)((jb+2)*(jb+2)))
            + q3*(ii + (float)((jb+3)*(jb+3)));
    }

    __shared__ float smax[256]; __shared__ int sidx[256];
    __shared__ float rf[256], r0[256], ri[256], rj[256], rq[256];
    smax[t] = best; sidx[t] = bidx;
    rf[t] = sf; r0[t] = s0; ri[t] = si; rj[t] = sj; rq[t] = sq;
    __syncthreads();

    for (int off = 128; off > 0; off >>= 1) {
        if (t < off) {
            float vo = smax[t + off]; int io = sidx[t + off];
            if (vo > smax[t] || (vo == smax[t] && io < sidx[t])) { smax[t] = vo; sidx[t] = io; }
            rf[t] += rf[t + off]; r0[t] += r0[t + off];
            ri[t] += ri[t + off]; rj[t] += rj[t + off]; rq[t] += rq[t + off];
        }
        __syncthreads();
    }

    if (t == 0) {
        int mi = sidx[0] >> 7, mj = sidx[0] & 127;
        double T0 = r0[0], TI = ri[0], TJ = rj[0], TQ = rq[0];
        double dis = (double)(mi*mi + mj*mj) * T0 + TQ - 2.0*mi*TI - 2.0*mj*TJ;
        atomicAdd(&ws[0], (double)rf[0]);
        atomicAdd(&ws[1], T0);
        atomicAdd(&ws[2], dis);
    }
}

// One thread per pixel (b,h,w): top-2 over 64 channels held in registers,
// accumulate A1 = sum f^2*mo^2 and A2 = sum f^2*mo.
__global__ __launch_bounds__(256) void k2_pixel(const float* __restrict__ feat,
                                                double* __restrict__ ws) {
    const int t = threadIdx.x;
    const int p = blockIdx.x * 256 + t;   // pixel in [0, B*HW)
    const int b  = p >> 14;               // / 16384
    const int hw = p & 16383;
    const float* src = feat + (size_t)b * CDIM * HW + hw;

    float v[CDIM];
    #pragma unroll
    for (int c = 0; c < CDIM; ++c) v[c] = src[(size_t)c * HW];

    float m1 = -INFINITY, m2 = -INFINITY; int idx1 = 0;
    #pragma unroll
    for (int c = 0; c < CDIM; ++c) {
        float x = v[c];
        if (x > m1)      { m2 = m1; m1 = x; idx1 = c; }
        else if (x > m2) { m2 = x; }
    }

    float a1 = 0.f, a2 = 0.f;
    #pragma unroll
    for (int c = 0; c < CDIM; ++c) {
        float x = v[c], f2 = x * x;
        float mo = (c == idx1) ? m2 : m1;
        a1 += f2 * mo * mo;
        a2 += f2 * mo;
    }

    __shared__ float r1[256], r2[256];
    r1[t] = a1; r2[t] = a2;
    __syncthreads();
    for (int off = 128; off > 0; off >>= 1) {
        if (t < off) { r1[t] += r1[t + off]; r2[t] += r2[t + off]; }
        __syncthreads();
    }
    if (t == 0) {
        atomicAdd(&ws[3], (double)r1[0]);
        atomicAdd(&ws[4], (double)r2[0]);
    }
}

__global__ void k3_final(const double* __restrict__ ws, float* __restrict__ out) {
    const double n = 33554432.0; // 32*64*128*128
    double mgr = ws[0] / n;
    out[0] = (float)(ws[2] / n);
    out[1] = (float)((ws[3] - 2.0 * mgr * ws[4] + mgr * mgr * ws[1]) / n);
}

extern "C" void kernel_launch(void* const* d_in, const int* in_sizes, int n_in,
                              void* d_out, int out_size, void* d_ws, size_t ws_size,
                              hipStream_t stream) {
    const float* feat = (const float*)d_in[0];
    float* out = (float*)d_out;
    double* ws = (double*)d_ws;

    hipMemsetAsync(ws, 0, 5 * sizeof(double), stream);

    // B*C = 2048 channel blocks
    k1_channel<<<BDIM * CDIM, 256, 0, stream>>>(feat, ws);
    // B*H*W = 524288 pixels / 256 = 2048 blocks
    k2_pixel<<<(BDIM * HW) / 256, 256, 0, stream>>>(feat, ws);
    k3_final<<<1, 1, 0, stream>>>(ws, out);
}

// Round 2
// 65.268 us; speedup vs baseline: 2.4803x; 2.4803x over previous
//
#include <hip/hip_runtime.h>

#define HW    16384   // H*W
#define WDIM  128
#define CDIM  64
#define BDIM  32
#define NB1   (BDIM * CDIM)        // 2048 channel blocks
#define NB2   ((BDIM * HW) / 512)  // 1024 pixel-pair blocks (2 px/thread, 256 thr)

// ws layout (doubles):
//   [0      .. 2047]  per-block sum f        (k1)
//   [2048   .. 4095]  per-block sum f^2      (k1)
//   [4096   .. 6143]  per-block dis partial  (k1)
//   [6144   .. 7167]  per-block A1           (k2)
//   [7168   .. 8191]  per-block A2           (k2)

// One block per (b,c). Batched loads (16 float4 in flight), closed-form dis:
// sum f^2*((mi-i)^2+(mj-j)^2) = (mi^2+mj^2)*T0 + TQ - 2*mi*TI - 2*mj*TJ
__global__ __launch_bounds__(256) void k1_channel(const float* __restrict__ feat,
                                                  double* __restrict__ ws) {
    const int t = threadIdx.x;
    const size_t base = (size_t)blockIdx.x * HW;
    const float4* f4 = (const float4*)(feat + base);

    // Phase 1: issue all 16 loads (static indices -> registers, all in flight)
    float4 buf[16];
    #pragma unroll
    for (int k = 0; k < 16; ++k) buf[k] = f4[t + k * 256];

    // Phase 2: process
    float best = -INFINITY; int bidx = 0;
    float sf = 0.f, s0 = 0.f, si = 0.f, sj = 0.f, sq = 0.f;
    #pragma unroll
    for (int k = 0; k < 16; ++k) {
        int p = t + k * 256;
        int e = p * 4;                // element index; increases with k for fixed t
        int i  = e >> 7;
        int jb = e & 127;             // multiple of 4 -> no row crossing
        float x0 = buf[k].x, x1 = buf[k].y, x2 = buf[k].z, x3 = buf[k].w;
        if (x0 > best) { best = x0; bidx = e;     }
        if (x1 > best) { best = x1; bidx = e + 1; }
        if (x2 > best) { best = x2; bidx = e + 2; }
        if (x3 > best) { best = x3; bidx = e + 3; }
        float q0 = x0*x0, q1 = x1*x1, q2 = x2*x2, q3 = x3*x3;
        float qs = q0 + q1 + q2 + q3;
        sf += x0 + x1 + x2 + x3;
        s0 += qs;
        si += qs * (float)i;
        sj += q0*(float)jb + q1*(float)(jb+1) + q2*(float)(jb+2) + q3*(float)(jb+3);
        float ii = (float)(i * i);
        sq += q0*(ii + (float)( jb   * jb   ))
            + q1*(ii + (float)((jb+1)*(jb+1)))
            + q2*(ii + (float)((jb+2)*(jb+2)))
            + q3*(ii + (float)((jb+3)*(jb+3)));
    }

    __shared__ float smax[256]; __shared__ int sidx[256];
    __shared__ float rf[256], r0[256], ri[256], rj[256], rq[256];
    smax[t] = best; sidx[t] = bidx;
    rf[t] = sf; r0[t] = s0; ri[t] = si; rj[t] = sj; rq[t] = sq;
    __syncthreads();

    for (int off = 128; off > 0; off >>= 1) {
        if (t < off) {
            float vo = smax[t + off]; int io = sidx[t + off];
            if (vo > smax[t] || (vo == smax[t] && io < sidx[t])) { smax[t] = vo; sidx[t] = io; }
            rf[t] += rf[t + off]; r0[t] += r0[t + off];
            ri[t] += ri[t + off]; rj[t] += rj[t + off]; rq[t] += rq[t + off];
        }
        __syncthreads();
    }

    if (t == 0) {
        int mi = sidx[0] >> 7, mj = sidx[0] & 127;
        double T0 = r0[0], TI = ri[0], TJ = rj[0], TQ = rq[0];
        double dis = (double)(mi*mi + mj*mj) * T0 + TQ - 2.0*mi*TI - 2.0*mj*TJ;
        ws[blockIdx.x]        = (double)rf[0];
        ws[2048 + blockIdx.x] = T0;
        ws[4096 + blockIdx.x] = dis;
    }
}

// 2 pixels per thread (float2): top-2 over 64 channels in registers,
// A1 = sum f^2*mo^2, A2 = sum f^2*mo. Per-block partials, no atomics.
__global__ __launch_bounds__(256) void k2_pixel(const float* __restrict__ feat,
                                                double* __restrict__ ws) {
    const int t = threadIdx.x;
    const int pp = blockIdx.x * 256 + t;    // pixel-pair index [0, B*HW/2)
    const int b   = pp >> 13;               // 8192 pairs per image
    const int hw2 = pp & 8191;
    const float2* src = (const float2*)(feat + (size_t)b * CDIM * HW) + hw2;

    float2 v[CDIM];
    #pragma unroll
    for (int c = 0; c < CDIM; ++c) v[c] = src[c * (HW / 2)];

    float m1x = -INFINITY, m2x = -INFINITY; int i1x = 0;
    float m1y = -INFINITY, m2y = -INFINITY; int i1y = 0;
    #pragma unroll
    for (int c = 0; c < CDIM; ++c) {
        float x = v[c].x, y = v[c].y;
        if (x > m1x)      { m2x = m1x; m1x = x; i1x = c; }
        else if (x > m2x) { m2x = x; }
        if (y > m1y)      { m2y = m1y; m1y = y; i1y = c; }
        else if (y > m2y) { m2y = y; }
    }

    float a1 = 0.f, a2 = 0.f;
    #pragma unroll
    for (int c = 0; c < CDIM; ++c) {
        float x = v[c].x, y = v[c].y;
        float f2x = x * x, f2y = y * y;
        float mox = (c == i1x) ? m2x : m1x;
        float moy = (c == i1y) ? m2y : m1y;
        a1 += f2x * mox * mox + f2y * moy * moy;
        a2 += f2x * mox + f2y * moy;
    }

    __shared__ float r1[256], r2[256];
    r1[t] = a1; r2[t] = a2;
    __syncthreads();
    for (int off = 128; off > 0; off >>= 1) {
        if (t < off) { r1[t] += r1[t + off]; r2[t] += r2[t + off]; }
        __syncthreads();
    }
    if (t == 0) {
        ws[6144 + blockIdx.x] = (double)r1[0];
        ws[7168 + blockIdx.x] = (double)r2[0];
    }
}

// Single-block final reduction over per-block partials (all in double).
__global__ __launch_bounds__(256) void k3_final(const double* __restrict__ ws,
                                                float* __restrict__ out) {
    const int t = threadIdx.x;
    double sf = 0, s0 = 0, dis = 0, a1 = 0, a2 = 0;
    for (int i = t; i < 2048; i += 256) {
        sf  += ws[i];
        s0  += ws[2048 + i];
        dis += ws[4096 + i];
    }
    for (int i = t; i < 1024; i += 256) {
        a1 += ws[6144 + i];
        a2 += ws[7168 + i];
    }
    __shared__ double r[5][256];
    r[0][t] = sf; r[1][t] = s0; r[2][t] = dis; r[3][t] = a1; r[4][t] = a2;
    __syncthreads();
    for (int off = 128; off > 0; off >>= 1) {
        if (t < off) {
            #pragma unroll
            for (int q = 0; q < 5; ++q) r[q][t] += r[q][t + off];
        }
        __syncthreads();
    }
    if (t == 0) {
        const double n = 33554432.0; // 32*64*128*128
        double mgr = r[0][0] / n;
        out[0] = (float)(r[2][0] / n);
        out[1] = (float)((r[3][0] - 2.0 * mgr * r[4][0] + mgr * mgr * r[1][0]) / n);
    }
}

extern "C" void kernel_launch(void* const* d_in, const int* in_sizes, int n_in,
                              void* d_out, int out_size, void* d_ws, size_t ws_size,
                              hipStream_t stream) {
    const float* feat = (const float*)d_in[0];
    float* out = (float*)d_out;
    double* ws = (double*)d_ws;

    k1_channel<<<NB1, 256, 0, stream>>>(feat, ws);
    k2_pixel<<<NB2, 256, 0, stream>>>(feat, ws);
    k3_final<<<1, 256, 0, stream>>>(ws, out);
}

// Round 3
// 58.909 us; speedup vs baseline: 2.7480x; 1.1079x over previous
//
#include <hip/hip_runtime.h>

#define HW    16384   // H*W
#define WDIM  128
#define CDIM  64
#define BDIM  32
#define NB1   (BDIM * CDIM)         // 2048 channel blocks
#define NB2   ((BDIM * HW) / 1024)  // 512 pixel blocks (4 px/thread via float4, 256 thr)

// ws layout (doubles):
//   [0      .. 2047]  per-block sum f        (k1)
//   [2048   .. 4095]  per-block sum f^2      (k1)
//   [4096   .. 6143]  per-block dis partial  (k1)
//   [6144   .. 6655]  per-block A1           (k2)
//   [6656   .. 7167]  per-block A2           (k2)

// One block per (b,c). Batched loads (16 float4 in flight), closed-form dis:
// sum f^2*((mi-i)^2+(mj-j)^2) = (mi^2+mj^2)*T0 + TQ - 2*mi*TI - 2*mj*TJ
__global__ __launch_bounds__(256) void k1_channel(const float* __restrict__ feat,
                                                  double* __restrict__ ws) {
    const int t = threadIdx.x;
    const size_t base = (size_t)blockIdx.x * HW;
    const float4* f4 = (const float4*)(feat + base);

    float4 buf[16];
    #pragma unroll
    for (int k = 0; k < 16; ++k) buf[k] = f4[t + k * 256];

    float best = -INFINITY; int bidx = 0;
    float sf = 0.f, s0 = 0.f, si = 0.f, sj = 0.f, sq = 0.f;
    #pragma unroll
    for (int k = 0; k < 16; ++k) {
        int p = t + k * 256;
        int e = p * 4;
        int i  = e >> 7;
        int jb = e & 127;
        float x0 = buf[k].x, x1 = buf[k].y, x2 = buf[k].z, x3 = buf[k].w;
        if (x0 > best) { best = x0; bidx = e;     }
        if (x1 > best) { best = x1; bidx = e + 1; }
        if (x2 > best) { best = x2; bidx = e + 2; }
        if (x3 > best) { best = x3; bidx = e + 3; }
        float q0 = x0*x0, q1 = x1*x1, q2 = x2*x2, q3 = x3*x3;
        float qs = q0 + q1 + q2 + q3;
        sf += x0 + x1 + x2 + x3;
        s0 += qs;
        si += qs * (float)i;
        sj += q0*(float)jb + q1*(float)(jb+1) + q2*(float)(jb+2) + q3*(float)(jb+3);
        float ii = (float)(i * i);
        sq += q0*(ii + (float)( jb   * jb   ))
            + q1*(ii + (float)((jb+1)*(jb+1)))
            + q2*(ii + (float)((jb+2)*(jb+2)))
            + q3*(ii + (float)((jb+3)*(jb+3)));
    }

    __shared__ float smax[256]; __shared__ int sidx[256];
    __shared__ float rf[256], r0[256], ri[256], rj[256], rq[256];
    smax[t] = best; sidx[t] = bidx;
    rf[t] = sf; r0[t] = s0; ri[t] = si; rj[t] = sj; rq[t] = sq;
    __syncthreads();

    for (int off = 128; off > 0; off >>= 1) {
        if (t < off) {
            float vo = smax[t + off]; int io = sidx[t + off];
            if (vo > smax[t] || (vo == smax[t] && io < sidx[t])) { smax[t] = vo; sidx[t] = io; }
            rf[t] += rf[t + off]; r0[t] += r0[t + off];
            ri[t] += ri[t + off]; rj[t] += rj[t + off]; rq[t] += rq[t + off];
        }
        __syncthreads();
    }

    if (t == 0) {
        int mi = sidx[0] >> 7, mj = sidx[0] & 127;
        double T0 = r0[0], TI = ri[0], TJ = rj[0], TQ = rq[0];
        double dis = (double)(mi*mi + mj*mj) * T0 + TQ - 2.0*mi*TI - 2.0*mj*TJ;
        ws[blockIdx.x]        = (double)rf[0];
        ws[2048 + blockIdx.x] = T0;
        ws[4096 + blockIdx.x] = dis;
    }
}

// Streaming per-pixel kernel, 4 px/thread via float4. No register array:
// per pixel track top-2 (m1,m2) and S2 = sum_c f^2, then closed form:
//   A1_px = m1^2*(S2 - m1^2) + m2^2*m1^2
//   A2_px = m1 *(S2 - m1^2) + m2 *m1^2
// (max_others = m1 for all channels except the argmax one, where f^2 = m1^2,
//  mo = m2; ties give identical results by symmetry.)
__global__ __launch_bounds__(256) void k2_pixel(const float* __restrict__ feat,
                                                double* __restrict__ ws) {
    const int t = threadIdx.x;
    const int p4 = blockIdx.x * 256 + t;     // float4 index in [0, B*HW/4)
    const int b   = p4 >> 12;                // 4096 float4s per image
    const int hw4 = p4 & 4095;
    const float4* src = (const float4*)(feat + (size_t)b * CDIM * HW) + hw4;

    float m1x=-INFINITY, m2x=-INFINITY, s2x=0.f;
    float m1y=-INFINITY, m2y=-INFINITY, s2y=0.f;
    float m1z=-INFINITY, m2z=-INFINITY, s2z=0.f;
    float m1w=-INFINITY, m2w=-INFINITY, s2w=0.f;

    #pragma unroll
    for (int c = 0; c < CDIM; ++c) {
        float4 v = src[c * (HW / 4)];
        if (v.x > m1x) { m2x = m1x; m1x = v.x; } else { m2x = fmaxf(m2x, v.x); }
        if (v.y > m1y) { m2y = m1y; m1y = v.y; } else { m2y = fmaxf(m2y, v.y); }
        if (v.z > m1z) { m2z = m1z; m1z = v.z; } else { m2z = fmaxf(m2z, v.z); }
        if (v.w > m1w) { m2w = m1w; m1w = v.w; } else { m2w = fmaxf(m2w, v.w); }
        s2x = fmaf(v.x, v.x, s2x);
        s2y = fmaf(v.y, v.y, s2y);
        s2z = fmaf(v.z, v.z, s2z);
        s2w = fmaf(v.w, v.w, s2w);
    }

    float a1, a2;
    {
        float qx = m1x*m1x, qy = m1y*m1y, qz = m1z*m1z, qw = m1w*m1w;
        float rx = s2x - qx, ry = s2y - qy, rz = s2z - qz, rw = s2w - qw;
        a1 = qx*rx + m2x*m2x*qx
           + qy*ry + m2y*m2y*qy
           + qz*rz + m2z*m2z*qz
           + qw*rw + m2w*m2w*qw;
        a2 = m1x*rx + m2x*qx
           + m1y*ry + m2y*qy
           + m1z*rz + m2z*qz
           + m1w*rw + m2w*qw;
    }

    __shared__ float r1[256], r2[256];
    r1[t] = a1; r2[t] = a2;
    __syncthreads();
    for (int off = 128; off > 0; off >>= 1) {
        if (t < off) { r1[t] += r1[t + off]; r2[t] += r2[t + off]; }
        __syncthreads();
    }
    if (t == 0) {
        ws[6144 + blockIdx.x]       = (double)r1[0];
        ws[6144 + NB2 + blockIdx.x] = (double)r2[0];
    }
}

// Single-block final reduction over per-block partials (all in double).
__global__ __launch_bounds__(256) void k3_final(const double* __restrict__ ws,
                                                float* __restrict__ out) {
    const int t = threadIdx.x;
    double sf = 0, s0 = 0, dis = 0, a1 = 0, a2 = 0;
    for (int i = t; i < NB1; i += 256) {
        sf  += ws[i];
        s0  += ws[2048 + i];
        dis += ws[4096 + i];
    }
    for (int i = t; i < NB2; i += 256) {
        a1 += ws[6144 + i];
        a2 += ws[6144 + NB2 + i];
    }
    __shared__ double r[5][256];
    r[0][t] = sf; r[1][t] = s0; r[2][t] = dis; r[3][t] = a1; r[4][t] = a2;
    __syncthreads();
    for (int off = 128; off > 0; off >>= 1) {
        if (t < off) {
            #pragma unroll
            for (int q = 0; q < 5; ++q) r[q][t] += r[q][t + off];
        }
        __syncthreads();
    }
    if (t == 0) {
        const double n = 33554432.0; // 32*64*128*128
        double mgr = r[0][0] / n;
        out[0] = (float)(r[2][0] / n);
        out[1] = (float)((r[3][0] - 2.0 * mgr * r[4][0] + mgr * mgr * r[1][0]) / n);
    }
}

extern "C" void kernel_launch(void* const* d_in, const int* in_sizes, int n_in,
                              void* d_out, int out_size, void* d_ws, size_t ws_size,
                              hipStream_t stream) {
    const float* feat = (const float*)d_in[0];
    float* out = (float*)d_out;
    double* ws = (double*)d_ws;

    k1_channel<<<NB1, 256, 0, stream>>>(feat, ws);
    k2_pixel<<<NB2, 256, 0, stream>>>(feat, ws);
    k3_final<<<1, 256, 0, stream>>>(ws, out);
}

// Round 4
// 55.054 us; speedup vs baseline: 2.9404x; 1.0700x over previous
//
#include <hip/hip_runtime.h>

#define HW     16384
#define WDIM   128
#define HDIM   128
#define CDIM   64
#define BDIM   32
#define CHUNKS 128                 // one block per (b, row): row has 128 px
#define NBF    (BDIM * CHUNKS)     // 4096 fused blocks
#define NBC    (BDIM * CDIM)       // 2048 (b,c) pairs

// ws layout (bytes):
//  0 MB : wmax  float[4096][64]   per (b,row,ch) row max
//  1 MB : widx  int  [4096][64]   argmax col within row
//  2 MB : wsf   float[4096][64]   sum f
//  3 MB : ws0   float[4096][64]   sum f^2
//  4 MB : wsj   float[4096][64]   sum f^2 * j
//  5 MB : wsqj  float[4096][64]   sum f^2 * j^2
//  6 MB          : wa1 double[4096]   per-block A1
//  6 MB + 32 KB  : wa2 double[4096]   per-block A2
//  6 MB + 64 KB  : k3out double[2048][3]  (sf, s0, dis) per (b,c)

#define OFF_WMAX  0
#define OFF_WIDX  (1u << 20)
#define OFF_WSF   (2u << 20)
#define OFF_WS0   (3u << 20)
#define OFF_WSJ   (4u << 20)
#define OFF_WSQJ  (5u << 20)
#define OFF_WA1   (6u << 20)
#define OFF_WA2   ((6u << 20) + 32768u)
#define OFF_K3    ((6u << 20) + 65536u)

// Fused single pass: block = (b, row). Tile = 64 ch x 128 px in LDS (stride 129,
// all phases <=2-way bank aliasing = free).
__global__ __launch_bounds__(256) void f_fused(const float* __restrict__ feat,
                                               float* __restrict__ wmax, int* __restrict__ widx,
                                               float* __restrict__ wsf,  float* __restrict__ ws0,
                                               float* __restrict__ wsj,  float* __restrict__ wsqj,
                                               double* __restrict__ wa1, double* __restrict__ wa2) {
    __shared__ float tile[CDIM * 129];      // 33024 B
    __shared__ float sc2[128 * 3];          // phase-2a half merge
    __shared__ float ared[128 * 2];         // per-pixel a1,a2
    __shared__ float scb[4 * 64 * 7];       // phase-2b sub partials (stride 7: conflict-free)

    const int t  = threadIdx.x;
    const int bf = blockIdx.x;              // b*128 + row
    const int b  = bf >> 7, row = bf & 127;
    const float* src = feat + (size_t)b * CDIM * HW + (size_t)row * WDIM;

    // ---- Phase 1: load 64ch x 128px (2048 float4), stage in LDS
    float4 buf[8];
    #pragma unroll
    for (int k = 0; k < 8; ++k) {
        int idx = k * 256 + t;              // f4 index: c = idx>>5, g = idx&31
        int c = idx >> 5, g = idx & 31;
        buf[k] = *(const float4*)(src + (size_t)c * HW + g * 4);
    }
    #pragma unroll
    for (int k = 0; k < 8; ++k) {
        int idx = k * 256 + t;
        int c = idx >> 5, g = idx & 31;
        float* dst = &tile[c * 129 + g * 4];
        dst[0] = buf[k].x; dst[1] = buf[k].y; dst[2] = buf[k].z; dst[3] = buf[k].w;
    }
    __syncthreads();

    // ---- Phase 2a: pixel-direction. thread t: px = t&127, half = t>>7 scans 32 ch.
    {
        const int px = t & 127, half = t >> 7;
        float m1 = -INFINITY, m2 = -INFINITY, s2 = 0.f;
        #pragma unroll
        for (int cc = 0; cc < 32; ++cc) {
            float x = tile[(half * 32 + cc) * 129 + px];
            if (x > m1) { m2 = m1; m1 = x; } else { m2 = fmaxf(m2, x); }
            s2 = fmaf(x, x, s2);
        }
        if (half) { sc2[px * 3] = m1; sc2[px * 3 + 1] = m2; sc2[px * 3 + 2] = s2; }
        __syncthreads();
        if (!half) {
            float n1 = sc2[px * 3], n2 = sc2[px * 3 + 1], s2b = sc2[px * 3 + 2];
            float mm1 = fmaxf(m1, n1);
            float mm2 = fmaxf(fminf(m1, n1), fmaxf(m2, n2));
            float S2 = s2 + s2b;
            float q = mm1 * mm1, r = S2 - q;
            ared[px * 2]     = q * r + mm2 * mm2 * q;       // a1
            ared[px * 2 + 1] = mm1 * r + mm2 * q;           // a2
        }
        __syncthreads();
        // tree-reduce 128 px by threads < 64 then < ...
        for (int off = 64; off > 0; off >>= 1) {
            if (t < off) {
                ared[t * 2]     += ared[(t + off) * 2];
                ared[t * 2 + 1] += ared[(t + off) * 2 + 1];
            }
            __syncthreads();
        }
        if (t == 0) { wa1[bf] = (double)ared[0]; wa2[bf] = (double)ared[1]; }
    }

    // ---- Phase 2b: channel-direction. thread t: ch = t&63, sub = t>>6 scans 32 px.
    {
        const int ch = t & 63, sub = t >> 6;
        const int p0 = sub * 32;
        float bm = -INFINITY; int bpx = 0;
        float sf = 0.f, s0 = 0.f, sj = 0.f, sqj = 0.f;
        #pragma unroll
        for (int i = 0; i < 32; ++i) {
            int p = p0 + i;
            float x = tile[ch * 129 + p];
            if (x > bm) { bm = x; bpx = p; }   // ascending p: strict > keeps first
            sf += x;
            float q = x * x;
            s0 += q;
            sj  = fmaf(q, (float)p, sj);
            sqj = fmaf(q, (float)(p * p), sqj);
        }
        int o = (sub * 64 + ch) * 7;
        scb[o] = bm; scb[o + 1] = __int_as_float(bpx);
        scb[o + 2] = sf; scb[o + 3] = s0; scb[o + 4] = sj; scb[o + 5] = sqj;
        __syncthreads();
        if (t < 64) {                          // combine 4 subs for channel t
            float M = -INFINITY; int P = 0;
            float SF = 0.f, S0 = 0.f, SJ = 0.f, SQ = 0.f;
            #pragma unroll
            for (int s = 0; s < 4; ++s) {      // ascending sub = ascending px: > keeps first
                int oo = (s * 64 + t) * 7;
                float m = scb[oo];
                if (m > M) { M = m; P = __float_as_int(scb[oo + 1]); }
                SF += scb[oo + 2]; S0 += scb[oo + 3];
                SJ += scb[oo + 4]; SQ += scb[oo + 5];
            }
            int out = bf * 64 + t;
            wmax[out] = M; widx[out] = P;
            wsf[out] = SF; ws0[out] = S0; wsj[out] = SJ; wsqj[out] = SQ;
        }
    }
}

// One block per (b,c): merge 128 row partials. Argmax (tie -> smaller row =
// first occurrence), then dis = sum_rows ((mi-row)^2 + mj^2)*s0 - 2*mj*sj + sqj.
__global__ __launch_bounds__(128) void k3_channel(const float* __restrict__ wmax, const int* __restrict__ widx,
                                                  const float* __restrict__ wsf,  const float* __restrict__ ws0,
                                                  const float* __restrict__ wsj,  const float* __restrict__ wsqj,
                                                  double* __restrict__ k3out) {
    const int bc = blockIdx.x;             // b*64 + c
    const int b = bc >> 6, c = bc & 63;
    const int t = threadIdx.x;             // row
    const int idx = (b * 128 + t) * 64 + c;

    float m = wmax[idx]; int px = widx[idx];
    float sf = wsf[idx], s0 = ws0[idx], sj = wsj[idx], sqj = wsqj[idx];

    __shared__ float rm[128]; __shared__ int rr[128]; __shared__ int rp[128];
    rm[t] = m; rr[t] = t; rp[t] = px;
    __syncthreads();
    for (int off = 64; off > 0; off >>= 1) {
        if (t < off) {
            float mo = rm[t + off];
            if (mo > rm[t] || (mo == rm[t] && rr[t + off] < rr[t])) {
                rm[t] = mo; rr[t] = rr[t + off]; rp[t] = rp[t + off];
            }
        }
        __syncthreads();
    }
    const int mi = rr[0], mj = rp[0];

    double di = (double)(mi - t);
    double disc = (di * di + (double)mj * (double)mj) * (double)s0
                - 2.0 * (double)mj * (double)sj + (double)sqj;

    __shared__ double rd[128], rsf[128], rs0[128];
    rd[t] = disc; rsf[t] = (double)sf; rs0[t] = (double)s0;
    __syncthreads();
    for (int off = 64; off > 0; off >>= 1) {
        if (t < off) { rd[t] += rd[t + off]; rsf[t] += rsf[t + off]; rs0[t] += rs0[t + off]; }
        __syncthreads();
    }
    if (t == 0) {
        k3out[bc * 3]     = rsf[0];
        k3out[bc * 3 + 1] = rs0[0];
        k3out[bc * 3 + 2] = rd[0];
    }
}

__global__ __launch_bounds__(256) void k4_final(const double* __restrict__ k3out,
                                                const double* __restrict__ wa1,
                                                const double* __restrict__ wa2,
                                                float* __restrict__ out) {
    const int t = threadIdx.x;
    double sf = 0, s0 = 0, dis = 0, a1 = 0, a2 = 0;
    for (int i = t; i < NBC; i += 256) {
        sf += k3out[i * 3]; s0 += k3out[i * 3 + 1]; dis += k3out[i * 3 + 2];
    }
    for (int i = t; i < NBF; i += 256) { a1 += wa1[i]; a2 += wa2[i]; }

    __shared__ double r[5][256];
    r[0][t] = sf; r[1][t] = s0; r[2][t] = dis; r[3][t] = a1; r[4][t] = a2;
    __syncthreads();
    for (int off = 128; off > 0; off >>= 1) {
        if (t < off) {
            #pragma unroll
            for (int q = 0; q < 5; ++q) r[q][t] += r[q][t + off];
        }
        __syncthreads();
    }
    if (t == 0) {
        const double n = 33554432.0; // 32*64*128*128
        double mgr = r[0][0] / n;
        out[0] = (float)(r[2][0] / n);
        out[1] = (float)((r[3][0] - 2.0 * mgr * r[4][0] + mgr * mgr * r[1][0]) / n);
    }
}

extern "C" void kernel_launch(void* const* d_in, const int* in_sizes, int n_in,
                              void* d_out, int out_size, void* d_ws, size_t ws_size,
                              hipStream_t stream) {
    const float* feat = (const float*)d_in[0];
    float* out = (float*)d_out;
    char* ws = (char*)d_ws;

    float*  wmax = (float*)(ws + OFF_WMAX);
    int*    widx = (int*)  (ws + OFF_WIDX);
    float*  wsf  = (float*)(ws + OFF_WSF);
    float*  ws0  = (float*)(ws + OFF_WS0);
    float*  wsj  = (float*)(ws + OFF_WSJ);
    float*  wsqj = (float*)(ws + OFF_WSQJ);
    double* wa1  = (double*)(ws + OFF_WA1);
    double* wa2  = (double*)(ws + OFF_WA2);
    double* k3o  = (double*)(ws + OFF_K3);

    f_fused<<<NBF, 256, 0, stream>>>(feat, wmax, widx, wsf, ws0, wsj, wsqj, wa1, wa2);
    k3_channel<<<NBC, 128, 0, stream>>>(wmax, widx, wsf, ws0, wsj, wsqj, k3o);
    k4_final<<<1, 256, 0, stream>>>(k3o, wa1, wa2, out);
}

// Round 5
// 54.890 us; speedup vs baseline: 2.9492x; 1.0030x over previous
//
#include <hip/hip_runtime.h>

#define HW     16384
#define WDIM   128
#define HDIM   128
#define CDIM   64
#define BDIM   32
#define CHUNKS 128                 // one block per (b, row): row has 128 px
#define NBF    (BDIM * CHUNKS)     // 4096 fused blocks
#define NBC    (BDIM * CDIM)       // 2048 (b,c) pairs

// ws layout (bytes):
//  0 MB : wmax  float[4096][64]   per (b,row,ch) row max
//  1 MB : widx  int  [4096][64]   argmax col within row
//  2 MB : wsf   float[4096][64]   sum f
//  3 MB : ws0   float[4096][64]   sum f^2
//  4 MB : wsj   float[4096][64]   sum f^2 * j
//  5 MB : wsqj  float[4096][64]   sum f^2 * j^2
//  6 MB          : wa1 double[4096]   per-block A1
//  6 MB + 32 KB  : wa2 double[4096]   per-block A2
//  6 MB + 64 KB  : k3out double[2048][3]  (sf, s0, dis) per (b,c)

#define OFF_WMAX  0
#define OFF_WIDX  (1u << 20)
#define OFF_WSF   (2u << 20)
#define OFF_WS0   (3u << 20)
#define OFF_WSJ   (4u << 20)
#define OFF_WSQJ  (5u << 20)
#define OFF_WA1   (6u << 20)
#define OFF_WA2   ((6u << 20) + 32768u)
#define OFF_K3    ((6u << 20) + 65536u)

// Fused single pass: block = (b, row). Tile = 64 ch x 128 px in LDS (stride 129,
// all phases <=2-way bank aliasing = free).
__global__ __launch_bounds__(256) void f_fused(const float* __restrict__ feat,
                                               float* __restrict__ wmax, int* __restrict__ widx,
                                               float* __restrict__ wsf,  float* __restrict__ ws0,
                                               float* __restrict__ wsj,  float* __restrict__ wsqj,
                                               double* __restrict__ wa1, double* __restrict__ wa2) {
    __shared__ float tile[CDIM * 129];      // 33024 B
    __shared__ float sc2[128 * 3];          // phase-2a half merge
    __shared__ float ared[128 * 2];         // per-pixel a1,a2
    __shared__ float scb[4 * 64 * 7];       // phase-2b sub partials (stride 7: conflict-free)

    const int t  = threadIdx.x;
    const int bf = blockIdx.x;              // b*128 + row
    const int b  = bf >> 7, row = bf & 127;
    const float* src = feat + (size_t)b * CDIM * HW + (size_t)row * WDIM;

    // ---- Phase 1: load 64ch x 128px (2048 float4), stage in LDS
    float4 buf[8];
    #pragma unroll
    for (int k = 0; k < 8; ++k) {
        int idx = k * 256 + t;              // f4 index: c = idx>>5, g = idx&31
        int c = idx >> 5, g = idx & 31;
        buf[k] = *(const float4*)(src + (size_t)c * HW + g * 4);
    }
    #pragma unroll
    for (int k = 0; k < 8; ++k) {
        int idx = k * 256 + t;
        int c = idx >> 5, g = idx & 31;
        float* dst = &tile[c * 129 + g * 4];
        dst[0] = buf[k].x; dst[1] = buf[k].y; dst[2] = buf[k].z; dst[3] = buf[k].w;
    }
    __syncthreads();

    // ---- Phase 2a: pixel-direction. thread t: px = t&127, half = t>>7 scans 32 ch.
    {
        const int px = t & 127, half = t >> 7;
        float m1 = -INFINITY, m2 = -INFINITY, s2 = 0.f;
        #pragma unroll
        for (int cc = 0; cc < 32; ++cc) {
            float x = tile[(half * 32 + cc) * 129 + px];
            if (x > m1) { m2 = m1; m1 = x; } else { m2 = fmaxf(m2, x); }
            s2 = fmaf(x, x, s2);
        }
        if (half) { sc2[px * 3] = m1; sc2[px * 3 + 1] = m2; sc2[px * 3 + 2] = s2; }
        __syncthreads();
        if (!half) {
            float n1 = sc2[px * 3], n2 = sc2[px * 3 + 1], s2b = sc2[px * 3 + 2];
            float mm1 = fmaxf(m1, n1);
            float mm2 = fmaxf(fminf(m1, n1), fmaxf(m2, n2));
            float S2 = s2 + s2b;
            float q = mm1 * mm1, r = S2 - q;
            ared[px * 2]     = q * r + mm2 * mm2 * q;       // a1
            ared[px * 2 + 1] = mm1 * r + mm2 * q;           // a2
        }
        __syncthreads();
        // tree-reduce 128 px by threads < 64 then < ...
        for (int off = 64; off > 0; off >>= 1) {
            if (t < off) {
                ared[t * 2]     += ared[(t + off) * 2];
                ared[t * 2 + 1] += ared[(t + off) * 2 + 1];
            }
            __syncthreads();
        }
        if (t == 0) { wa1[bf] = (double)ared[0]; wa2[bf] = (double)ared[1]; }
    }

    // ---- Phase 2b: channel-direction. thread t: ch = t&63, sub = t>>6 scans 32 px.
    {
        const int ch = t & 63, sub = t >> 6;
        const int p0 = sub * 32;
        float bm = -INFINITY; int bpx = 0;
        float sf = 0.f, s0 = 0.f, sj = 0.f, sqj = 0.f;
        #pragma unroll
        for (int i = 0; i < 32; ++i) {
            int p = p0 + i;
            float x = tile[ch * 129 + p];
            if (x > bm) { bm = x; bpx = p; }   // ascending p: strict > keeps first
            sf += x;
            float q = x * x;
            s0 += q;
            sj  = fmaf(q, (float)p, sj);
            sqj = fmaf(q, (float)(p * p), sqj);
        }
        int o = (sub * 64 + ch) * 7;
        scb[o] = bm; scb[o + 1] = __int_as_float(bpx);
        scb[o + 2] = sf; scb[o + 3] = s0; scb[o + 4] = sj; scb[o + 5] = sqj;
        __syncthreads();
        if (t < 64) {                          // combine 4 subs for channel t
            float M = -INFINITY; int P = 0;
            float SF = 0.f, S0 = 0.f, SJ = 0.f, SQ = 0.f;
            #pragma unroll
            for (int s = 0; s < 4; ++s) {      // ascending sub = ascending px: > keeps first
                int oo = (s * 64 + t) * 7;
                float m = scb[oo];
                if (m > M) { M = m; P = __float_as_int(scb[oo + 1]); }
                SF += scb[oo + 2]; S0 += scb[oo + 3];
                SJ += scb[oo + 4]; SQ += scb[oo + 5];
            }
            int out = bf * 64 + t;
            wmax[out] = M; widx[out] = P;
            wsf[out] = SF; ws0[out] = S0; wsj[out] = SJ; wsqj[out] = SQ;
        }
    }
}

// One block per (b,c): merge 128 row partials. Argmax (tie -> smaller row =
// first occurrence), then dis = sum_rows ((mi-row)^2 + mj^2)*s0 - 2*mj*sj + sqj.
__global__ __launch_bounds__(128) void k3_channel(const float* __restrict__ wmax, const int* __restrict__ widx,
                                                  const float* __restrict__ wsf,  const float* __restrict__ ws0,
                                                  const float* __restrict__ wsj,  const float* __restrict__ wsqj,
                                                  double* __restrict__ k3out) {
    const int bc = blockIdx.x;             // b*64 + c
    const int b = bc >> 6, c = bc & 63;
    const int t = threadIdx.x;             // row
    const int idx = (b * 128 + t) * 64 + c;

    float m = wmax[idx]; int px = widx[idx];
    float sf = wsf[idx], s0 = ws0[idx], sj = wsj[idx], sqj = wsqj[idx];

    __shared__ float rm[128]; __shared__ int rr[128]; __shared__ int rp[128];
    rm[t] = m; rr[t] = t; rp[t] = px;
    __syncthreads();
    for (int off = 64; off > 0; off >>= 1) {
        if (t < off) {
            float mo = rm[t + off];
            if (mo > rm[t] || (mo == rm[t] && rr[t + off] < rr[t])) {
                rm[t] = mo; rr[t] = rr[t + off]; rp[t] = rp[t + off];
            }
        }
        __syncthreads();
    }
    const int mi = rr[0], mj = rp[0];

    double di = (double)(mi - t);
    double disc = (di * di + (double)mj * (double)mj) * (double)s0
                - 2.0 * (double)mj * (double)sj + (double)sqj;

    __shared__ double rd[128], rsf[128], rs0[128];
    rd[t] = disc; rsf[t] = (double)sf; rs0[t] = (double)s0;
    __syncthreads();
    for (int off = 64; off > 0; off >>= 1) {
        if (t < off) { rd[t] += rd[t + off]; rsf[t] += rsf[t + off]; rs0[t] += rs0[t + off]; }
        __syncthreads();
    }
    if (t == 0) {
        k3out[bc * 3]     = rsf[0];
        k3out[bc * 3 + 1] = rs0[0];
        k3out[bc * 3 + 2] = rd[0];
    }
}

__global__ __launch_bounds__(256) void k4_final(const double* __restrict__ k3out,
                                                const double* __restrict__ wa1,
                                                const double* __restrict__ wa2,
                                                float* __restrict__ out) {
    const int t = threadIdx.x;
    double sf = 0, s0 = 0, dis = 0, a1 = 0, a2 = 0;
    for (int i = t; i < NBC; i += 256) {
        sf += k3out[i * 3]; s0 += k3out[i * 3 + 1]; dis += k3out[i * 3 + 2];
    }
    for (int i = t; i < NBF; i += 256) { a1 += wa1[i]; a2 += wa2[i]; }

    __shared__ double r[5][256];
    r[0][t] = sf; r[1][t] = s0; r[2][t] = dis; r[3][t] = a1; r[4][t] = a2;
    __syncthreads();
    for (int off = 128; off > 0; off >>= 1) {
        if (t < off) {
            #pragma unroll
            for (int q = 0; q < 5; ++q) r[q][t] += r[q][t + off];
        }
        __syncthreads();
    }
    if (t == 0) {
        const double n = 33554432.0; // 32*64*128*128
        double mgr = r[0][0] / n;
        out[0] = (float)(r[2][0] / n);
        out[1] = (float)((r[3][0] - 2.0 * mgr * r[4][0] + mgr * mgr * r[1][0]) / n);
    }
}

extern "C" void kernel_launch(void* const* d_in, const int* in_sizes, int n_in,
                              void* d_out, int out_size, void* d_ws, size_t ws_size,
                              hipStream_t stream) {
    const float* feat = (const float*)d_in[0];
    float* out = (float*)d_out;
    char* ws = (char*)d_ws;

    float*  wmax = (float*)(ws + OFF_WMAX);
    int*    widx = (int*)  (ws + OFF_WIDX);
    float*  wsf  = (float*)(ws + OFF_WSF);
    float*  ws0  = (float*)(ws + OFF_WS0);
    float*  wsj  = (float*)(ws + OFF_WSJ);
    float*  wsqj = (float*)(ws + OFF_WSQJ);
    double* wa1  = (double*)(ws + OFF_WA1);
    double* wa2  = (double*)(ws + OFF_WA2);
    double* k3o  = (double*)(ws + OFF_K3);

    f_fused<<<NBF, 256, 0, stream>>>(feat, wmax, widx, wsf, ws0, wsj, wsqj, wa1, wa2);
    k3_channel<<<NBC, 128, 0, stream>>>(wmax, widx, wsf, ws0, wsj, wsqj, k3o);
    k4_final<<<1, 256, 0, stream>>>(k3o, wa1, wa2, out);
}

// Round 6
// 53.685 us; speedup vs baseline: 3.0154x; 1.0224x over previous
//
#include <hip/hip_runtime.h>

#define HW     16384
#define WDIM   128
#define CDIM   64
#define BDIM   32
#define NBF    4096     // (b,row) blocks
#define NBC    2048     // (b,c) pairs

// ws layout (bytes). Per-channel partial arrays are C-MAJOR [64][4096] so
// k3_channel reads are unit-stride coalesced.
#define OFF_WMAX  0
#define OFF_WIDX  (1u << 20)
#define OFF_WSF   (2u << 20)
#define OFF_WS0   (3u << 20)
#define OFF_WSJ   (4u << 20)
#define OFF_WSQJ  (5u << 20)
#define OFF_WA1   (6u << 20)
#define OFF_WA2   ((6u << 20) + 32768u)
#define OFF_K3    ((6u << 20) + 65536u)

// Fused single pass: block = (b, row). Tile 64ch x 128px in LDS (stride 129:
// every access pattern is <=2-way bank aliasing = free). 4 barriers total,
// 40.2 KB LDS -> 4 blocks/CU for phase overlap.
__global__ __launch_bounds__(256, 4) void f_fused(const float* __restrict__ feat,
                                                  float* __restrict__ wmax, int* __restrict__ widx,
                                                  float* __restrict__ wsf,  float* __restrict__ ws0,
                                                  float* __restrict__ wsj,  float* __restrict__ wsqj,
                                                  double* __restrict__ wa1, double* __restrict__ wa2) {
    __shared__ float tile[CDIM * 129];      // 33024 B
    __shared__ float scratch[1792];         // union: 2a sc2[128*3] -> 2b scb[4*64*7]
    __shared__ float sred[4];               // a1,a2 wave partials

    const int t  = threadIdx.x;
    const int bf = blockIdx.x;              // b*128 + row
    const int b  = bf >> 7, row = bf & 127;
    const float* src = feat + (size_t)b * CDIM * HW + (size_t)row * WDIM;

    // ---- Phase 1: load 64ch x 128px (batched float4), stage to LDS
    float4 buf[8];
    #pragma unroll
    for (int k = 0; k < 8; ++k) {
        int idx = k * 256 + t;              // c = idx>>5, g = idx&31
        int c = idx >> 5, g = idx & 31;
        buf[k] = *(const float4*)(src + (size_t)c * HW + g * 4);
    }
    #pragma unroll
    for (int k = 0; k < 8; ++k) {
        int idx = k * 256 + t;
        int c = idx >> 5, g = idx & 31;
        float* dst = &tile[c * 129 + g * 4];
        dst[0] = buf[k].x; dst[1] = buf[k].y; dst[2] = buf[k].z; dst[3] = buf[k].w;
    }
    __syncthreads();   // B1

    // ---- Phase 2a scan: thread t -> px = t&127, half = t>>7 scans 32 ch
    const int px = t & 127, half = t >> 7;
    float m1 = -INFINITY, m2 = -INFINITY, s2 = 0.f;
    #pragma unroll
    for (int cc = 0; cc < 32; ++cc) {
        float x = tile[(half * 32 + cc) * 129 + px];
        if (x > m1) { m2 = m1; m1 = x; } else { m2 = fmaxf(m2, x); }
        s2 = fmaf(x, x, s2);
    }
    if (half) { scratch[px * 3] = m1; scratch[px * 3 + 1] = m2; scratch[px * 3 + 2] = s2; }
    __syncthreads();   // B2

    // ---- Phase 2b scan (ALL threads, from stable tile): ch = t&63, sub = t>>6
    const int ch = t & 63, sub = t >> 6, p0 = sub * 32;
    float bm = -INFINITY; int bi = 0;
    float sf = 0.f, s0 = 0.f, sjl = 0.f, sql = 0.f;
    #pragma unroll
    for (int i = 0; i < 32; ++i) {
        float x = tile[ch * 129 + p0 + i];
        if (x > bm) { bm = x; bi = i; }      // ascending i: strict > keeps first
        sf += x;
        float q = x * x;
        s0 += q;
        sjl = fmaf(q, (float)i, sjl);        // i compile-time const
        sql = fmaf(q, (float)(i * i), sql);
    }

    // ---- 2a merge + shfl reduce (waves 0-1 only; px == t, wave-uniform branch)
    if (!half) {
        float n1 = scratch[px * 3], n2 = scratch[px * 3 + 1], s2b = scratch[px * 3 + 2];
        float mm1 = fmaxf(m1, n1);
        float mm2 = fmaxf(fminf(m1, n1), fmaxf(m2, n2));
        float S2 = s2 + s2b;
        float qq = mm1 * mm1, rr = S2 - qq;
        float a1 = qq * rr + mm2 * mm2 * qq;
        float a2 = mm1 * rr + mm2 * qq;
        #pragma unroll
        for (int off = 32; off > 0; off >>= 1) {
            a1 += __shfl_down(a1, off);
            a2 += __shfl_down(a2, off);
        }
        if (t == 0)  { sred[0] = a1; sred[1] = a2; }
        if (t == 64) { sred[2] = a1; sred[3] = a2; }
    }
    __syncthreads();   // B3 (sc2 reads done -> scratch reusable; sred visible)

    // ---- write 2b sub-partials (scb region of the union)
    {
        float sj  = fmaf((float)p0, s0, sjl);                          // sum q*(p0+i)
        float sqj = fmaf((float)(p0 * p0), s0, fmaf(2.f * (float)p0, sjl, sql));
        int o = (sub * 64 + ch) * 7;
        scratch[o]     = bm;
        scratch[o + 1] = __int_as_float(p0 + bi);
        scratch[o + 2] = sf; scratch[o + 3] = s0;
        scratch[o + 4] = sj; scratch[o + 5] = sqj;
    }
    if (t == 255) {
        wa1[bf] = (double)(sred[0] + sred[2]);
        wa2[bf] = (double)(sred[1] + sred[3]);
    }
    __syncthreads();   // B4

    // ---- combine 4 subs per channel, write c-major partials
    if (t < 64) {
        float M = -INFINITY; int P = 0;
        float SF = 0.f, S0 = 0.f, SJ = 0.f, SQ = 0.f;
        #pragma unroll
        for (int s = 0; s < 4; ++s) {        // ascending sub = ascending px
            int oo = (s * 64 + t) * 7;
            float m = scratch[oo];
            if (m > M) { M = m; P = __float_as_int(scratch[oo + 1]); }
            SF += scratch[oo + 2]; S0 += scratch[oo + 3];
            SJ += scratch[oo + 4]; SQ += scratch[oo + 5];
        }
        int out = t * 4096 + bf;             // [c][4096] c-major
        wmax[out] = M; widx[out] = P;
        wsf[out] = SF; ws0[out] = S0; wsj[out] = SJ; wsqj[out] = SQ;
    }
}

// One block per (b,c): merge 128 row partials (now unit-stride coalesced).
// dis = sum_rows ((mi-row)^2 + mj^2)*s0 - 2*mj*sj + sqj.
__global__ __launch_bounds__(128) void k3_channel(const float* __restrict__ wmax, const int* __restrict__ widx,
                                                  const float* __restrict__ wsf,  const float* __restrict__ ws0,
                                                  const float* __restrict__ wsj,  const float* __restrict__ wsqj,
                                                  double* __restrict__ k3out) {
    const int bc = blockIdx.x;             // b*64 + c
    const int b = bc >> 6, c = bc & 63;
    const int t = threadIdx.x;             // row
    const int idx = c * 4096 + b * 128 + t;

    float m = wmax[idx]; int px = widx[idx];
    float sf = wsf[idx], s0 = ws0[idx], sj = wsj[idx], sqj = wsqj[idx];

    __shared__ float rm[128]; __shared__ int rr[128]; __shared__ int rp[128];
    rm[t] = m; rr[t] = t; rp[t] = px;
    __syncthreads();
    for (int off = 64; off > 0; off >>= 1) {
        if (t < off) {
            float mo = rm[t + off];
            if (mo > rm[t] || (mo == rm[t] && rr[t + off] < rr[t])) {
                rm[t] = mo; rr[t] = rr[t + off]; rp[t] = rp[t + off];
            }
        }
        __syncthreads();
    }
    const int mi = rr[0], mj = rp[0];

    double di = (double)(mi - t);
    double disc = (di * di + (double)mj * (double)mj) * (double)s0
                - 2.0 * (double)mj * (double)sj + (double)sqj;

    __shared__ double rd[128], rsf[128], rs0[128];
    rd[t] = disc; rsf[t] = (double)sf; rs0[t] = (double)s0;
    __syncthreads();
    for (int off = 64; off > 0; off >>= 1) {
        if (t < off) { rd[t] += rd[t + off]; rsf[t] += rsf[t + off]; rs0[t] += rs0[t + off]; }
        __syncthreads();
    }
    if (t == 0) {
        k3out[bc * 3]     = rsf[0];
        k3out[bc * 3 + 1] = rs0[0];
        k3out[bc * 3 + 2] = rd[0];
    }
}

__global__ __launch_bounds__(256) void k4_final(const double* __restrict__ k3out,
                                                const double* __restrict__ wa1,
                                                const double* __restrict__ wa2,
                                                float* __restrict__ out) {
    const int t = threadIdx.x;
    double sf = 0, s0 = 0, dis = 0, a1 = 0, a2 = 0;
    for (int i = t; i < NBC; i += 256) {
        sf += k3out[i * 3]; s0 += k3out[i * 3 + 1]; dis += k3out[i * 3 + 2];
    }
    for (int i = t; i < NBF; i += 256) { a1 += wa1[i]; a2 += wa2[i]; }

    __shared__ double r[5][256];
    r[0][t] = sf; r[1][t] = s0; r[2][t] = dis; r[3][t] = a1; r[4][t] = a2;
    __syncthreads();
    for (int off = 128; off > 0; off >>= 1) {
        if (t < off) {
            #pragma unroll
            for (int q = 0; q < 5; ++q) r[q][t] += r[q][t + off];
        }
        __syncthreads();
    }
    if (t == 0) {
        const double n = 33554432.0; // 32*64*128*128
        double mgr = r[0][0] / n;
        out[0] = (float)(r[2][0] / n);
        out[1] = (float)((r[3][0] - 2.0 * mgr * r[4][0] + mgr * mgr * r[1][0]) / n);
    }
}

extern "C" void kernel_launch(void* const* d_in, const int* in_sizes, int n_in,
                              void* d_out, int out_size, void* d_ws, size_t ws_size,
                              hipStream_t stream) {
    const float* feat = (const float*)d_in[0];
    float* out = (float*)d_out;
    char* ws = (char*)d_ws;

    float*  wmax = (float*)(ws + OFF_WMAX);
    int*    widx = (int*)  (ws + OFF_WIDX);
    float*  wsf  = (float*)(ws + OFF_WSF);
    float*  ws0  = (float*)(ws + OFF_WS0);
    float*  wsj  = (float*)(ws + OFF_WSJ);
    float*  wsqj = (float*)(ws + OFF_WSQJ);
    double* wa1  = (double*)(ws + OFF_WA1);
    double* wa2  = (double*)(ws + OFF_WA2);
    double* k3o  = (double*)(ws + OFF_K3);

    f_fused<<<NBF, 256, 0, stream>>>(feat, wmax, widx, wsf, ws0, wsj, wsqj, wa1, wa2);
    k3_channel<<<NBC, 128, 0, stream>>>(wmax, widx, wsf, ws0, wsj, wsqj, k3o);
    k4_final<<<1, 256, 0, stream>>>(k3o, wa1, wa2, out);
}